// Round 1
// 866.590 us; speedup vs baseline: 1.0777x; 1.0777x over previous
//
#include <hip/hip_runtime.h>

#define CONF_THRESHOLD 0.01f
#define LOC_VAR 0.1f
#define SIZE_VAR 0.2f

// Tiling: 48 rows per block.
//  - 48*85 = 4080 floats = 16320 B LDS  -> 8 blocks/CU (130 KB of 160 KB), 100% occupancy
//  - 48*85*4 B chunk size is 16B-aligned -> float4 staging loads
//  - R = 64*24564 = 1,572,096 is divisible by 48 (32,752 blocks), tail paths kept for safety
#define CH 48
#define CHF (CH * 85)    // 4080 floats staged per block
#define CHF4 (CHF / 4)   // 1020 float4
#define CCONF (CH * 81)  // 3888 indicator elements per block

__global__ __launch_bounds__(256, 8) void infbox_tiled(
    const float4* __restrict__ pred4,
    const float* __restrict__ pred,      // scalar alias of the same buffer (tail path)
    const float4* __restrict__ dboxes,
    float* __restrict__ out,
    int NA, unsigned int R) {
    __shared__ float lds[CHF];

    const unsigned int tid = threadIdx.x;
    const unsigned int blk = blockIdx.x;
    const size_t rowbase = (size_t)blk * CH;   // first row owned by this block
    const size_t fbase = rowbase * 85u;        // first float of the chunk
    const size_t F = (size_t)R * 85u;          // total floats in pred

    // ---- stage 48 rows into LDS: lane-contiguous float4 loads ----
    if (fbase + CHF <= F) {
        const size_t b4 = fbase >> 2;          // fbase = blk*4080, divisible by 4
        float4* lds4 = (float4*)lds;
#pragma unroll
        for (unsigned int i = 0; i < 4; ++i) {
            unsigned int idx = tid + i * 256u;
            if (idx < CHF4) lds4[idx] = pred4[b4 + idx];
        }
    } else {
        // generic tail chunk (not hit for the bench shapes)
        for (unsigned int i = tid; i < CHF; i += 256u) {
            size_t f = fbase + i;
            lds[i] = (f < F) ? pred[f] : 0.0f;
        }
    }
    __syncthreads();

    // ---- boxes: 48 lanes, LDS stride 85 (≡21 mod 32 banks -> conflict-free) ----
    if (tid < CH) {
        size_t row = rowbase + tid;
        if (row < R) {
            unsigned int la = tid * 85u;
            float l0 = lds[la + 0];
            float l1 = lds[la + 1];
            float l2 = lds[la + 2];
            float l3 = lds[la + 3];
            unsigned int r32 = (unsigned int)row;
            float4 db = dboxes[r32 % (unsigned int)NA];
            float cx = db.x + l0 * LOC_VAR * db.z;
            float cy = db.y + l1 * LOC_VAR * db.w;
            float w  = db.z * expf(l2 * SIZE_VAR);
            float h  = db.w * expf(l3 * SIZE_VAR);
            float4 o;
            o.x = cx - w * 0.5f;
            o.y = cy - h * 0.5f;
            o.z = cx + w * 0.5f;
            o.w = cy + h * 0.5f;
            ((float4*)out)[row] = o;
        }
    }

    // ---- indicator: element-wise, lanes stride-1 on both LDS read and global store ----
    {
        const size_t M = (size_t)R * 81u;
        const size_t gc0 = (size_t)blk * CCONF;    // global conf index of this block's elem 0
        float* __restrict__ outc = out + (size_t)R * 4u;

        if (gc0 + CCONF <= M) {
            // full chunk: no per-element bounds checks, incremental a/c rollover
            unsigned int a = tid / 81u;            // one magic-div per thread
            unsigned int c = tid - a * 81u;
            unsigned int addr = a * 85u + 4u + c;  // LDS float index
#pragma unroll
            for (unsigned int i = 0; i < 16; ++i) {
                unsigned int e = tid + i * 256u;
                if (i < 15 || e < CCONF) {         // 3888 = 15*256 + 48
                    float v = lds[addr];
                    outc[gc0 + e] = (v > CONF_THRESHOLD) ? 1.0f : 0.0f;
                }
                // advance by 256 elements: +3 rows +13 cols (256 = 3*81 + 13)
                c += 13u;
                addr += 268u;                      // 3*85 + 13
                if (c >= 81u) { c -= 81u; addr += 4u; }
            }
        } else {
            // generic tail chunk
            for (unsigned int e = tid; e < CCONF; e += 256u) {
                size_t g = gc0 + e;
                if (g < M) {
                    unsigned int aa = e / 81u;
                    unsigned int cc = e - aa * 81u;
                    float v = lds[aa * 85u + 4u + cc];
                    outc[g] = (v > CONF_THRESHOLD) ? 1.0f : 0.0f;
                }
            }
        }
    }
}

extern "C" void kernel_launch(void* const* d_in, const int* in_sizes, int n_in,
                              void* d_out, int out_size, void* d_ws, size_t ws_size,
                              hipStream_t stream) {
    const float* predicts = (const float*)d_in[0];
    const float* dboxes   = (const float*)d_in[1];
    float* out = (float*)d_out;

    const int NA = in_sizes[1] / 4;                       // 24564 anchors
    const unsigned int R = (unsigned int)(out_size / 85); // B*NA rows

    const unsigned int grid = (R + (unsigned int)CH - 1u) / (unsigned int)CH;
    infbox_tiled<<<grid, 256, 0, stream>>>((const float4*)predicts, predicts,
                                           (const float4*)dboxes, out, NA, R);
}